// Round 1
// baseline (49.830 us; speedup 1.0000x reference)
//
#include <hip/hip_runtime.h>
#include <cfloat>

#define KK 5
#define BB 8
#define NN 200
#define DD 512

// ---------------------------------------------------------------------------
// Kernel A: per-batch distances + top-5 (smallest) + z_score; also re-inits
// the min-maps in workspace to +INF (ws is NOT re-poisoned between replays).
// ---------------------------------------------------------------------------
__global__ __launch_bounds__(256) void topk_init_kernel(
    const float* __restrict__ z, const float* __restrict__ zlib,
    float* __restrict__ zscore, int* __restrict__ idx_out,
    unsigned* __restrict__ minmaps, int mm_total)
{
    int b   = blockIdx.x;   // 0..7
    int tid = threadIdx.x;  // 0..255

    // init all min-maps to +inf (0x7F800000)
    for (int i = b * 256 + tid; i < mm_total; i += BB * 256)
        minmaps[i] = 0x7F800000u;

    __shared__ float zs[DD];
    __shared__ float dist[NN];
    for (int i = tid; i < DD; i += 256) zs[i] = z[b * DD + i];
    __syncthreads();

    for (int n = tid; n < NN; n += 256) {
        const float* lrow = zlib + (size_t)n * DD;
        float zz = 0.f, ll = 0.f, dot = 0.f;
        for (int c = 0; c < DD; ++c) {
            float a = zs[c], l = lrow[c];
            zz  = fmaf(a, a, zz);
            ll  = fmaf(l, l, ll);
            dot = fmaf(a, l, dot);
        }
        float d2 = zz + ll - 2.f * dot;
        dist[n] = sqrtf(fmaxf(d2, 0.f));
    }
    __syncthreads();

    __shared__ float sval[256];
    __shared__ int   sidx[256];
    float sum = 0.f;
    for (int it = 0; it < KK; ++it) {
        sval[tid] = (tid < NN) ? dist[tid] : FLT_MAX;
        sidx[tid] = tid;
        __syncthreads();
        for (int s = 128; s > 0; s >>= 1) {
            if (tid < s) {
                float v2 = sval[tid + s]; int i2 = sidx[tid + s];
                if (v2 < sval[tid] || (v2 == sval[tid] && i2 < sidx[tid])) {
                    sval[tid] = v2; sidx[tid] = i2;
                }
            }
            __syncthreads();
        }
        if (tid == 0) {
            int sel = sidx[0];
            idx_out[b * KK + it] = sel;
            sum += sval[0];
            dist[sel] = FLT_MAX;   // exclude for next round
        }
        __syncthreads();
    }
    if (tid == 0) zscore[b] = sum * (1.f / KK);
}

// ---------------------------------------------------------------------------
// Kernel B: per-(b,k,pixel) sum over channels of squared diff, atomicMin into
// per-scale min-map (float-as-uint is order-preserving for non-negative).
// ---------------------------------------------------------------------------
template <int C, int HW>
__device__ __forceinline__ void smap_body(
    const float* __restrict__ fmap, const float* __restrict__ lib,
    const int* __restrict__ idx, unsigned* __restrict__ mm, int gid)
{
    if (gid >= BB * KK * HW) return;
    int hw = gid % HW;
    int bk = gid / HW;
    int k  = bk % KK;
    int b  = bk / KK;
    int id = idx[b * KK + k];

    const float* f = fmap + (size_t)b  * C * HW + hw;
    const float* l = lib  + (size_t)id * C * HW + hw;

    float acc = 0.f;
#pragma unroll 16
    for (int c = 0; c < C; ++c) {
        float d = l[(size_t)c * HW] - f[(size_t)c * HW];
        acc = fmaf(d, d, acc);
    }
    atomicMin(&mm[b * HW + hw], __float_as_uint(acc));
}

__global__ __launch_bounds__(256) void smap_kernel(
    const float* __restrict__ fmap0, const float* __restrict__ fmap1,
    const float* __restrict__ fmap2,
    const float* __restrict__ lib0, const float* __restrict__ lib1,
    const float* __restrict__ lib2,
    const int* __restrict__ idx,
    unsigned* __restrict__ mm0, unsigned* __restrict__ mm1,
    unsigned* __restrict__ mm2,
    int nb0, int nb1)
{
    int blk = blockIdx.x;
    if (blk < nb0) {
        smap_body<64, 3136>(fmap0, lib0, idx, mm0, blk * 256 + threadIdx.x);
    } else if (blk < nb0 + nb1) {
        smap_body<128, 784>(fmap1, lib1, idx, mm1, (blk - nb0) * 256 + threadIdx.x);
    } else {
        smap_body<256, 196>(fmap2, lib2, idx, mm2, (blk - nb0 - nb1) * 256 + threadIdx.x);
    }
}

// ---------------------------------------------------------------------------
// Kernel C: bilinear upsample (half-pixel, edge-clamped == jax.image.resize
// "bilinear" for pure upsampling) of the 3 min-maps to 224x224, summed.
// ---------------------------------------------------------------------------
__device__ __forceinline__ float bil(const unsigned* __restrict__ m, int S,
                                     int oy, int ox)
{
    float scale = (float)S * (1.f / 224.f);
    float sy = fminf(fmaxf((oy + 0.5f) * scale - 0.5f, 0.f), (float)(S - 1));
    float sx = fminf(fmaxf((ox + 0.5f) * scale - 0.5f, 0.f), (float)(S - 1));
    int y0 = (int)sy, x0 = (int)sx;
    float ty = sy - y0, tx = sx - x0;
    int y1 = min(y0 + 1, S - 1), x1 = min(x0 + 1, S - 1);
    float v00 = __uint_as_float(m[y0 * S + x0]);
    float v01 = __uint_as_float(m[y0 * S + x1]);
    float v10 = __uint_as_float(m[y1 * S + x0]);
    float v11 = __uint_as_float(m[y1 * S + x1]);
    float top = v00 + tx * (v01 - v00);
    float bot = v10 + tx * (v11 - v10);
    return top + ty * (bot - top);
}

__global__ __launch_bounds__(256) void upsample_kernel(
    const unsigned* __restrict__ mm0, const unsigned* __restrict__ mm1,
    const unsigned* __restrict__ mm2, float* __restrict__ out)
{
    int gid = blockIdx.x * 256 + threadIdx.x;   // over 8*224*224
    if (gid >= BB * 224 * 224) return;
    int ox = gid % 224;
    int r  = gid / 224;
    int oy = r % 224;
    int b  = r / 224;

    float v = bil(mm0 + b * 3136, 56, oy, ox)
            + bil(mm1 + b * 784,  28, oy, ox)
            + bil(mm2 + b * 196,  14, oy, ox);
    out[BB + gid] = v;   // first 8 floats are z_score
}

// ---------------------------------------------------------------------------
extern "C" void kernel_launch(void* const* d_in, const int* in_sizes, int n_in,
                              void* d_out, int out_size, void* d_ws, size_t ws_size,
                              hipStream_t stream)
{
    const float* z     = (const float*)d_in[0];
    const float* zlib  = (const float*)d_in[1];
    const float* fmap0 = (const float*)d_in[2];
    const float* fmap1 = (const float*)d_in[3];
    const float* fmap2 = (const float*)d_in[4];
    const float* lib0  = (const float*)d_in[5];
    const float* lib1  = (const float*)d_in[6];
    const float* lib2  = (const float*)d_in[7];
    float* out = (float*)d_out;

    char* ws = (char*)d_ws;
    int* idx       = (int*)ws;                       // 40 ints
    unsigned* mm0  = (unsigned*)(ws + 256);          // 8*3136
    unsigned* mm1  = mm0 + BB * 3136;                // 8*784
    unsigned* mm2  = mm1 + BB * 784;                 // 8*196
    const int mm_total = BB * (3136 + 784 + 196);    // 32928

    topk_init_kernel<<<BB, 256, 0, stream>>>(z, zlib, out, idx, mm0, mm_total);

    // block ranges: scale0: 8*5*3136/256 = 490; scale1: ceil(31360/256)=123;
    // scale2: ceil(7840/256)=31  -> 644 blocks total
    smap_kernel<<<644, 256, 0, stream>>>(fmap0, fmap1, fmap2,
                                         lib0, lib1, lib2,
                                         idx, mm0, mm1, mm2, 490, 123);

    upsample_kernel<<<1568, 256, 0, stream>>>(mm0, mm1, mm2, out);
}